// Round 1
// baseline (1372.102 us; speedup 1.0000x reference)
//
#include <hip/hip_runtime.h>
#include <math.h>

#define NNODES 100000
#define NEDGES 3200000
#define F 128

// ---------------- degree / norm ----------------

__global__ void degree_kernel(const int* __restrict__ src, const int* __restrict__ dst,
                              int* __restrict__ deg_out, int* __restrict__ deg_in) {
    int e = blockIdx.x * blockDim.x + threadIdx.x;
    if (e < NEDGES) {
        atomicAdd(&deg_out[src[e]], 1);
        atomicAdd(&deg_in[dst[e]], 1);
    }
}

__global__ void norm_kernel(const int* __restrict__ deg_out, const int* __restrict__ deg_in,
                            float* __restrict__ out_norm, float* __restrict__ in_norm) {
    int i = blockIdx.x * blockDim.x + threadIdx.x;
    if (i < NNODES) {
        int dovr = deg_out[i]; if (dovr < 1) dovr = 1;
        int divr = deg_in[i];  if (divr < 1) divr = 1;
        out_norm[i] = 1.0f / sqrtf((float)dovr);
        in_norm[i]  = 1.0f / sqrtf((float)divr);
    }
}

// ---------------- CSR build (counts -> exclusive scan -> scatter) ----------------

__global__ void scan1_kernel(const int* __restrict__ counts, int* __restrict__ row_ptr,
                             int* __restrict__ blocksums) {
    __shared__ int s[256];
    int t = threadIdx.x;
    int idx = blockIdx.x * 256 + t;
    int v = (idx < NNODES) ? counts[idx] : 0;
    s[t] = v;
    __syncthreads();
    for (int off = 1; off < 256; off <<= 1) {
        int u = (t >= off) ? s[t - off] : 0;
        __syncthreads();
        s[t] += u;
        __syncthreads();
    }
    if (idx < NNODES) row_ptr[idx + 1] = s[t];
    if (t == 255) blocksums[blockIdx.x] = s[255];
}

__global__ void scan2_kernel(int* __restrict__ blocksums, int nb) {
    if (threadIdx.x == 0 && blockIdx.x == 0) {
        int run = 0;
        for (int b = 0; b < nb; b++) { int v = blocksums[b]; blocksums[b] = run; run += v; }
    }
}

__global__ void scan3_kernel(int* __restrict__ row_ptr, const int* __restrict__ blocksums,
                             int* __restrict__ cursor) {
    int idx = blockIdx.x * 256 + threadIdx.x;
    if (idx < NNODES) {
        int v = row_ptr[idx + 1] + blocksums[idx >> 8];
        row_ptr[idx + 1] = v;
        if (idx + 1 < NNODES) cursor[idx + 1] = v;
        if (idx == 0) { row_ptr[0] = 0; cursor[0] = 0; }
    }
}

__global__ void fill_kernel(const int* __restrict__ src, const int* __restrict__ dst,
                            int* __restrict__ cursor, int* __restrict__ csr_src) {
    int e = blockIdx.x * blockDim.x + threadIdx.x;
    if (e < NEDGES) {
        int p = atomicAdd(&cursor[dst[e]], 1);
        csr_src[p] = src[e];
    }
}

// ---------------- aggregation: one wave per dst node, atomic-free ----------------
// out[node] = in_norm[node] * sum_{e: dst==node} h[src_e] * out_norm[src_e]

__global__ void aggregate_kernel(const float* __restrict__ h, const int* __restrict__ row_ptr,
                                 const int* __restrict__ csr_src,
                                 const float* __restrict__ out_norm,
                                 const float* __restrict__ in_norm,
                                 float* __restrict__ out) {
    int wave = threadIdx.x >> 6;
    int lane = threadIdx.x & 63;
    int node = blockIdx.x * 4 + wave;
    if (node >= NNODES) return;
    int beg = row_ptr[node], end = row_ptr[node + 1];
    float ax = 0.f, ay = 0.f;
    int l2 = lane * 2;
    int j = beg;
    for (; j + 4 <= end; j += 4) {
        int s0 = csr_src[j], s1 = csr_src[j + 1], s2 = csr_src[j + 2], s3 = csr_src[j + 3];
        float n0 = out_norm[s0], n1 = out_norm[s1], n2 = out_norm[s2], n3 = out_norm[s3];
        float2 v0 = *(const float2*)(h + (size_t)s0 * F + l2);
        float2 v1 = *(const float2*)(h + (size_t)s1 * F + l2);
        float2 v2 = *(const float2*)(h + (size_t)s2 * F + l2);
        float2 v3 = *(const float2*)(h + (size_t)s3 * F + l2);
        ax += v0.x * n0 + v1.x * n1 + v2.x * n2 + v3.x * n3;
        ay += v0.y * n0 + v1.y * n1 + v2.y * n2 + v3.y * n3;
    }
    for (; j < end; j++) {
        int s0 = csr_src[j];
        float n0 = out_norm[s0];
        float2 v0 = *(const float2*)(h + (size_t)s0 * F + l2);
        ax += v0.x * n0;
        ay += v0.y * n0;
    }
    float inn = in_norm[node];
    float2 r;
    r.x = ax * inn;
    r.y = ay * inn;
    *(float2*)(out + (size_t)node * F + l2) = r;
}

// ---------------- fused GEMM + bias + activation ----------------
// C[nrows x NCOL] = act(A[nrows x 128] @ W[128 x NCOL] + bias)
// ACT: 0=none, 1=relu, 2=sigmoid

template <int NCOL, int ACT>
__global__ __launch_bounds__(256) void gemm_act_kernel(const float* __restrict__ A,
                                                       const float* __restrict__ W,
                                                       const float* __restrict__ bias,
                                                       float* __restrict__ C, int nrows) {
    constexpr int TM = 64;
    constexpr int CT = NCOL / 4;   // threads covering columns (float4 each)
    constexpr int RG = 256 / CT;   // row groups
    constexpr int RPT = TM / RG;   // rows per thread
    __shared__ float As[TM][132];  // +4 pad: LDS aliasing <=2-way (free)
    int row0 = blockIdx.x * TM;

    for (int i = threadIdx.x; i < TM * 32; i += 256) {
        int r = i >> 5, c4 = (i & 31) * 4;
        float4 v = make_float4(0.f, 0.f, 0.f, 0.f);
        int gr = row0 + r;
        if (gr < nrows) v = *(const float4*)(A + (size_t)gr * F + c4);
        *(float4*)(&As[r][c4]) = v;
    }
    __syncthreads();

    int ct = threadIdx.x % CT;
    int rg = threadIdx.x / CT;
    int col = ct * 4;
    float acc[RPT][4];
#pragma unroll
    for (int r = 0; r < RPT; r++) { acc[r][0] = acc[r][1] = acc[r][2] = acc[r][3] = 0.f; }

    for (int k4 = 0; k4 < F; k4 += 4) {
        float4 w0 = *(const float4*)(W + (size_t)(k4 + 0) * NCOL + col);
        float4 w1 = *(const float4*)(W + (size_t)(k4 + 1) * NCOL + col);
        float4 w2 = *(const float4*)(W + (size_t)(k4 + 2) * NCOL + col);
        float4 w3 = *(const float4*)(W + (size_t)(k4 + 3) * NCOL + col);
#pragma unroll
        for (int r = 0; r < RPT; r++) {
            float4 a = *(const float4*)(&As[rg * RPT + r][k4]);
            acc[r][0] += a.x * w0.x + a.y * w1.x + a.z * w2.x + a.w * w3.x;
            acc[r][1] += a.x * w0.y + a.y * w1.y + a.z * w2.y + a.w * w3.y;
            acc[r][2] += a.x * w0.z + a.y * w1.z + a.z * w2.z + a.w * w3.z;
            acc[r][3] += a.x * w0.w + a.y * w1.w + a.z * w2.w + a.w * w3.w;
        }
    }

    float4 bv = *(const float4*)(bias + col);
#pragma unroll
    for (int r = 0; r < RPT; r++) {
        int gr = row0 + rg * RPT + r;
        if (gr < nrows) {
            float4 o;
            o.x = acc[r][0] + bv.x;
            o.y = acc[r][1] + bv.y;
            o.z = acc[r][2] + bv.z;
            o.w = acc[r][3] + bv.w;
            if (ACT == 1) {
                o.x = fmaxf(o.x, 0.f); o.y = fmaxf(o.y, 0.f);
                o.z = fmaxf(o.z, 0.f); o.w = fmaxf(o.w, 0.f);
            } else if (ACT == 2) {
                o.x = 1.f / (1.f + __expf(-o.x));
                o.y = 1.f / (1.f + __expf(-o.y));
                o.z = 1.f / (1.f + __expf(-o.z));
                o.w = 1.f / (1.f + __expf(-o.w));
            }
            *(float4*)(C + (size_t)gr * NCOL + col) = o;
        }
    }
}

// ---------------- launch ----------------

extern "C" void kernel_launch(void* const* d_in, const int* in_sizes, int n_in,
                              void* d_out, int out_size, void* d_ws, size_t ws_size,
                              hipStream_t stream) {
    const float* x   = (const float*)d_in[0];
    const int* src   = (const int*)d_in[1];
    const int* dst   = (const int*)d_in[2];
    const float* W1  = (const float*)d_in[3];
    const float* b1  = (const float*)d_in[4];
    const float* W2  = (const float*)d_in[5];
    const float* b2  = (const float*)d_in[6];
    const float* Wm1 = (const float*)d_in[7];
    const float* bm1 = (const float*)d_in[8];
    const float* Wm2 = (const float*)d_in[9];
    const float* bm2 = (const float*)d_in[10];
    float* out = (float*)d_out;

    // workspace layout (~118 MB total)
    char* w = (char*)d_ws;
    int* deg_out   = (int*)w;   w += (size_t)NNODES * 4;
    int* deg_in    = (int*)w;   w += (size_t)NNODES * 4;
    float* out_norm = (float*)w; w += (size_t)NNODES * 4;
    float* in_norm  = (float*)w; w += (size_t)NNODES * 4;
    int* row_ptr   = (int*)w;   w += (size_t)(NNODES + 4) * 4;
    int* cursor    = (int*)w;   w += (size_t)NNODES * 4;
    int* blocksums = (int*)w;   w += 1024 * 4;
    int* csr_src   = (int*)w;   w += (size_t)NEDGES * 4;
    float* bufA    = (float*)w; w += (size_t)NNODES * F * 4;
    float* bufB    = (float*)w; w += (size_t)NNODES * F * 4;

    const int nbN = (NNODES + 255) / 256;   // 391
    const int nbE = (NEDGES + 255) / 256;

    hipMemsetAsync(deg_out, 0, (size_t)NNODES * 8, stream);  // deg_out + deg_in contiguous

    degree_kernel<<<nbE, 256, 0, stream>>>(src, dst, deg_out, deg_in);
    norm_kernel<<<nbN, 256, 0, stream>>>(deg_out, deg_in, out_norm, in_norm);
    scan1_kernel<<<nbN, 256, 0, stream>>>(deg_in, row_ptr, blocksums);
    scan2_kernel<<<1, 64, 0, stream>>>(blocksums, nbN);
    scan3_kernel<<<nbN, 256, 0, stream>>>(row_ptr, blocksums, cursor);
    fill_kernel<<<nbE, 256, 0, stream>>>(src, dst, cursor, csr_src);

    const int aggGrid = NNODES / 4;            // 4 waves/block, 1 node/wave
    const int gemmGrid = (NNODES + 63) / 64;

    // conv1: agg(x) -> bufB ; relu(bufB@W1+b1) -> bufA
    aggregate_kernel<<<aggGrid, 256, 0, stream>>>(x, row_ptr, csr_src, out_norm, in_norm, bufB);
    gemm_act_kernel<128, 1><<<gemmGrid, 256, 0, stream>>>(bufB, W1, b1, bufA, NNODES);
    // conv2: agg(bufA) -> bufB ; relu(bufB@W2+b2) -> bufA
    aggregate_kernel<<<aggGrid, 256, 0, stream>>>(bufA, row_ptr, csr_src, out_norm, in_norm, bufB);
    gemm_act_kernel<128, 1><<<gemmGrid, 256, 0, stream>>>(bufB, W2, b2, bufA, NNODES);
    // MLP head
    gemm_act_kernel<128, 1><<<gemmGrid, 256, 0, stream>>>(bufA, Wm1, bm1, bufB, NNODES);
    gemm_act_kernel<64, 2><<<gemmGrid, 256, 0, stream>>>(bufB, Wm2, bm2, out, NNODES);
}

// Round 2
// 1031.176 us; speedup vs baseline: 1.3306x; 1.3306x over previous
//
#include <hip/hip_runtime.h>
#include <math.h>

#define NNODES 100000
#define NEDGES 3200000
#define F 128
#define NPB 512                      // nodes per coarse bucket
#define NB ((NNODES + NPB - 1) / NPB) // 196 buckets
#define T2 8192                      // edges per bin_scatter block

// ---------------- pass 1: bucket histogram + out-degree ----------------

__global__ __launch_bounds__(256) void bin_count_kernel(const int* __restrict__ src,
                                                        const int* __restrict__ dst,
                                                        int* __restrict__ deg_out,
                                                        int* __restrict__ bucket_count) {
    __shared__ int hist[NB];
    for (int i = threadIdx.x; i < NB; i += 256) hist[i] = 0;
    __syncthreads();
    int stride = gridDim.x * 256;
    for (int e = blockIdx.x * 256 + threadIdx.x; e < NEDGES; e += stride) {
        atomicAdd(&deg_out[src[e]], 1);
        atomicAdd(&hist[dst[e] >> 9], 1);
    }
    __syncthreads();
    for (int i = threadIdx.x; i < NB; i += 256)
        if (hist[i]) atomicAdd(&bucket_count[i], hist[i]);
}

__global__ void outnorm_kernel(const int* __restrict__ deg_out, float* __restrict__ out_norm) {
    int i = blockIdx.x * 256 + threadIdx.x;
    if (i < NNODES) out_norm[i] = rsqrtf((float)max(deg_out[i], 1));
}

// ---------------- bucket offsets (exclusive scan over 196 counts) ----------------

__global__ void bucket_scan_kernel(const int* __restrict__ bucket_count,
                                   int* __restrict__ bucket_base,
                                   int* __restrict__ bucket_cursor) {
    __shared__ int s[256];
    int t = threadIdx.x;
    int v = (t < NB) ? bucket_count[t] : 0;
    s[t] = v;
    __syncthreads();
    for (int d = 1; d < 256; d <<= 1) {
        int u = (t >= d) ? s[t - d] : 0;
        __syncthreads();
        s[t] += u;
        __syncthreads();
    }
    if (t < NB) {
        int excl = s[t] - v;
        bucket_base[t] = excl;
        bucket_cursor[t] = excl;
        if (t == NB - 1) bucket_base[NB] = s[t];
    }
}

// ---------------- pass 2: coarse scatter, LDS-staged, contiguous runs ----------------

__global__ __launch_bounds__(256) void bin_scatter_kernel(const int* __restrict__ src,
                                                          const int* __restrict__ dst,
                                                          int* __restrict__ bucket_cursor,
                                                          unsigned int* __restrict__ edges_binned) {
    __shared__ unsigned int pk[T2];
    __shared__ unsigned char bb[T2];
    __shared__ int hist[NB], base[NB], lcur[NB];
    int t = threadIdx.x;
    for (int i = t; i < NB; i += 256) { hist[i] = 0; lcur[i] = 0; }
    __syncthreads();
    int e0 = blockIdx.x * T2;
    int n = min(T2, NEDGES - e0);
    for (int i = t; i < n; i += 256) {
        int s = src[e0 + i], d = dst[e0 + i];
        int b = d >> 9;
        pk[i] = (unsigned)s | ((unsigned)(d & (NPB - 1)) << 17);
        bb[i] = (unsigned char)b;
        atomicAdd(&hist[b], 1);
    }
    __syncthreads();
    for (int b = t; b < NB; b += 256)
        if (hist[b] > 0) base[b] = atomicAdd(&bucket_cursor[b], hist[b]);
    __syncthreads();
    for (int i = t; i < n; i += 256) {
        int b = bb[i];
        int pos = base[b] + atomicAdd(&lcur[b], 1);
        edges_binned[pos] = pk[i];
    }
}

// ---------------- pass 3: per-bucket fine CSR + in_norm (all-LDS cursors) ----------------

__global__ __launch_bounds__(512) void bucket_csr_kernel(const unsigned int* __restrict__ edges_binned,
                                                         const int* __restrict__ bucket_base,
                                                         int* __restrict__ row_ptr,
                                                         float* __restrict__ in_norm,
                                                         int* __restrict__ csr_src) {
    __shared__ int hist[NPB], off[NPB], lcur[NPB];
    int t = threadIdx.x;
    int b = blockIdx.x;
    hist[t] = 0; lcur[t] = 0;
    __syncthreads();
    int e0 = bucket_base[b], e1 = bucket_base[b + 1];
    for (int i = e0 + t; i < e1; i += 512)
        atomicAdd(&hist[edges_binned[i] >> 17], 1);
    __syncthreads();
    int h = hist[t];
    off[t] = h;
    __syncthreads();
    for (int d = 1; d < NPB; d <<= 1) {
        int u = (t >= d) ? off[t - d] : 0;
        __syncthreads();
        off[t] += u;
        __syncthreads();
    }
    int excl = off[t] - h;
    int node = b * NPB + t;
    if (node <= NNODES) row_ptr[node] = e0 + excl;
    if (node < NNODES) in_norm[node] = rsqrtf((float)max(h, 1));
    __syncthreads();
    off[t] = excl;
    __syncthreads();
    for (int i = e0 + t; i < e1; i += 512) {
        unsigned int p = edges_binned[i];
        int dl = p >> 17;
        int pos = e0 + off[dl] + atomicAdd(&lcur[dl], 1);
        csr_src[pos] = (int)(p & 0x1FFFF);
    }
}

// ---------------- aggregation: one wave per dst node, atomic-free ----------------

__global__ void aggregate_kernel(const float* __restrict__ h, const int* __restrict__ row_ptr,
                                 const int* __restrict__ csr_src,
                                 const float* __restrict__ out_norm,
                                 const float* __restrict__ in_norm,
                                 float* __restrict__ out) {
    int wave = threadIdx.x >> 6;
    int lane = threadIdx.x & 63;
    int node = blockIdx.x * 4 + wave;
    if (node >= NNODES) return;
    int beg = row_ptr[node], end = row_ptr[node + 1];
    float ax = 0.f, ay = 0.f;
    int l2 = lane * 2;
    int j = beg;
    for (; j + 4 <= end; j += 4) {
        int s0 = csr_src[j], s1 = csr_src[j + 1], s2 = csr_src[j + 2], s3 = csr_src[j + 3];
        float n0 = out_norm[s0], n1 = out_norm[s1], n2 = out_norm[s2], n3 = out_norm[s3];
        float2 v0 = *(const float2*)(h + (size_t)s0 * F + l2);
        float2 v1 = *(const float2*)(h + (size_t)s1 * F + l2);
        float2 v2 = *(const float2*)(h + (size_t)s2 * F + l2);
        float2 v3 = *(const float2*)(h + (size_t)s3 * F + l2);
        ax += v0.x * n0 + v1.x * n1 + v2.x * n2 + v3.x * n3;
        ay += v0.y * n0 + v1.y * n1 + v2.y * n2 + v3.y * n3;
    }
    for (; j < end; j++) {
        int s0 = csr_src[j];
        float n0 = out_norm[s0];
        float2 v0 = *(const float2*)(h + (size_t)s0 * F + l2);
        ax += v0.x * n0;
        ay += v0.y * n0;
    }
    float inn = in_norm[node];
    float2 r;
    r.x = ax * inn;
    r.y = ay * inn;
    *(float2*)(out + (size_t)node * F + l2) = r;
}

// ---------------- fused GEMM + bias + activation ----------------

template <int NCOL, int ACT>
__global__ __launch_bounds__(256) void gemm_act_kernel(const float* __restrict__ A,
                                                       const float* __restrict__ W,
                                                       const float* __restrict__ bias,
                                                       float* __restrict__ C, int nrows) {
    constexpr int TM = 64;
    constexpr int CT = NCOL / 4;
    constexpr int RG = 256 / CT;
    constexpr int RPT = TM / RG;
    __shared__ float As[TM][132];
    int row0 = blockIdx.x * TM;

    for (int i = threadIdx.x; i < TM * 32; i += 256) {
        int r = i >> 5, c4 = (i & 31) * 4;
        float4 v = make_float4(0.f, 0.f, 0.f, 0.f);
        int gr = row0 + r;
        if (gr < nrows) v = *(const float4*)(A + (size_t)gr * F + c4);
        *(float4*)(&As[r][c4]) = v;
    }
    __syncthreads();

    int ct = threadIdx.x % CT;
    int rg = threadIdx.x / CT;
    int col = ct * 4;
    float acc[RPT][4];
#pragma unroll
    for (int r = 0; r < RPT; r++) { acc[r][0] = acc[r][1] = acc[r][2] = acc[r][3] = 0.f; }

    for (int k4 = 0; k4 < F; k4 += 4) {
        float4 w0 = *(const float4*)(W + (size_t)(k4 + 0) * NCOL + col);
        float4 w1 = *(const float4*)(W + (size_t)(k4 + 1) * NCOL + col);
        float4 w2 = *(const float4*)(W + (size_t)(k4 + 2) * NCOL + col);
        float4 w3 = *(const float4*)(W + (size_t)(k4 + 3) * NCOL + col);
#pragma unroll
        for (int r = 0; r < RPT; r++) {
            float4 a = *(const float4*)(&As[rg * RPT + r][k4]);
            acc[r][0] += a.x * w0.x + a.y * w1.x + a.z * w2.x + a.w * w3.x;
            acc[r][1] += a.x * w0.y + a.y * w1.y + a.z * w2.y + a.w * w3.y;
            acc[r][2] += a.x * w0.z + a.y * w1.z + a.z * w2.z + a.w * w3.z;
            acc[r][3] += a.x * w0.w + a.y * w1.w + a.z * w2.w + a.w * w3.w;
        }
    }

    float4 bv = *(const float4*)(bias + col);
#pragma unroll
    for (int r = 0; r < RPT; r++) {
        int gr = row0 + rg * RPT + r;
        if (gr < nrows) {
            float4 o;
            o.x = acc[r][0] + bv.x;
            o.y = acc[r][1] + bv.y;
            o.z = acc[r][2] + bv.z;
            o.w = acc[r][3] + bv.w;
            if (ACT == 1) {
                o.x = fmaxf(o.x, 0.f); o.y = fmaxf(o.y, 0.f);
                o.z = fmaxf(o.z, 0.f); o.w = fmaxf(o.w, 0.f);
            } else if (ACT == 2) {
                o.x = 1.f / (1.f + __expf(-o.x));
                o.y = 1.f / (1.f + __expf(-o.y));
                o.z = 1.f / (1.f + __expf(-o.z));
                o.w = 1.f / (1.f + __expf(-o.w));
            }
            *(float4*)(C + (size_t)gr * NCOL + col) = o;
        }
    }
}

// ---------------- launch ----------------

extern "C" void kernel_launch(void* const* d_in, const int* in_sizes, int n_in,
                              void* d_out, int out_size, void* d_ws, size_t ws_size,
                              hipStream_t stream) {
    const float* x   = (const float*)d_in[0];
    const int* src   = (const int*)d_in[1];
    const int* dst   = (const int*)d_in[2];
    const float* W1  = (const float*)d_in[3];
    const float* b1  = (const float*)d_in[4];
    const float* W2  = (const float*)d_in[5];
    const float* b2  = (const float*)d_in[6];
    const float* Wm1 = (const float*)d_in[7];
    const float* bm1 = (const float*)d_in[8];
    const float* Wm2 = (const float*)d_in[9];
    const float* bm2 = (const float*)d_in[10];
    float* out = (float*)d_out;

    // workspace layout
    char* w = (char*)d_ws;
    int* deg_out      = (int*)w;   w += (size_t)NNODES * 4;
    int* bucket_count = (int*)w;   w += (size_t)(NB + 4) * 4;      // contiguous with deg_out for one memset
    float* out_norm   = (float*)w; w += (size_t)NNODES * 4;
    float* in_norm    = (float*)w; w += (size_t)NNODES * 4;
    int* row_ptr      = (int*)w;   w += (size_t)(NNODES + 4) * 4;
    int* bucket_base  = (int*)w;   w += (size_t)(NB + 4) * 4;
    int* bucket_cursor= (int*)w;   w += (size_t)(NB + 4) * 4;
    int* csr_src      = (int*)w;   w += (size_t)NEDGES * 4;
    float* bufA       = (float*)w; w += (size_t)NNODES * F * 4;
    float* bufB       = (float*)w; w += (size_t)NNODES * F * 4;
    // edges_binned (12.8 MB) aliases bufB (51.2 MB): dead before aggregate writes bufB
    unsigned int* edges_binned = (unsigned int*)bufB;

    const int nbN = (NNODES + 255) / 256;

    hipMemsetAsync(deg_out, 0, (size_t)(NNODES + NB + 4) * 4, stream);

    bin_count_kernel<<<1024, 256, 0, stream>>>(src, dst, deg_out, bucket_count);
    outnorm_kernel<<<nbN, 256, 0, stream>>>(deg_out, out_norm);
    bucket_scan_kernel<<<1, 256, 0, stream>>>(bucket_count, bucket_base, bucket_cursor);
    bin_scatter_kernel<<<(NEDGES + T2 - 1) / T2, 256, 0, stream>>>(src, dst, bucket_cursor, edges_binned);
    bucket_csr_kernel<<<NB, 512, 0, stream>>>(edges_binned, bucket_base, row_ptr, in_norm, csr_src);

    const int aggGrid = NNODES / 4;
    const int gemmGrid = (NNODES + 63) / 64;

    aggregate_kernel<<<aggGrid, 256, 0, stream>>>(x, row_ptr, csr_src, out_norm, in_norm, bufB);
    gemm_act_kernel<128, 1><<<gemmGrid, 256, 0, stream>>>(bufB, W1, b1, bufA, NNODES);
    aggregate_kernel<<<aggGrid, 256, 0, stream>>>(bufA, row_ptr, csr_src, out_norm, in_norm, bufB);
    gemm_act_kernel<128, 1><<<gemmGrid, 256, 0, stream>>>(bufB, W2, b2, bufA, NNODES);
    gemm_act_kernel<128, 1><<<gemmGrid, 256, 0, stream>>>(bufA, Wm1, bm1, bufB, NNODES);
    gemm_act_kernel<64, 2><<<gemmGrid, 256, 0, stream>>>(bufB, Wm2, bm2, out, NNODES);
}

// Round 3
// 716.599 us; speedup vs baseline: 1.9147x; 1.4390x over previous
//
#include <hip/hip_runtime.h>
#include <math.h>

#define NNODES 100000
#define NEDGES 3200000
#define F 128
#define NPB 512
#define NB ((NNODES + NPB - 1) / NPB)
#define T2 8192

typedef __attribute__((ext_vector_type(8))) short short8;
typedef __attribute__((ext_vector_type(4))) float f32x4;

__device__ __forceinline__ unsigned short f2bf(float f) {
    unsigned u = __float_as_uint(f);
    unsigned r = u + 0x7fff + ((u >> 16) & 1);
    return (unsigned short)(r >> 16);
}
__device__ __forceinline__ float bflo(unsigned u) { return __uint_as_float(u << 16); }
__device__ __forceinline__ float bfhi(unsigned u) { return __uint_as_float(u & 0xffff0000u); }

// ---------------- pass 1: bucket histogram + out-degree ----------------

__global__ __launch_bounds__(256) void bin_count_kernel(const int* __restrict__ src,
                                                        const int* __restrict__ dst,
                                                        int* __restrict__ deg_out,
                                                        int* __restrict__ bucket_count) {
    __shared__ int hist[NB];
    for (int i = threadIdx.x; i < NB; i += 256) hist[i] = 0;
    __syncthreads();
    int stride = gridDim.x * 256;
    for (int e = blockIdx.x * 256 + threadIdx.x; e < NEDGES; e += stride) {
        atomicAdd(&deg_out[src[e]], 1);
        atomicAdd(&hist[dst[e] >> 9], 1);
    }
    __syncthreads();
    for (int i = threadIdx.x; i < NB; i += 256)
        if (hist[i]) atomicAdd(&bucket_count[i], hist[i]);
}

__global__ void outnorm_kernel(const int* __restrict__ deg_out, float* __restrict__ out_norm) {
    int i = blockIdx.x * 256 + threadIdx.x;
    if (i < NNODES) out_norm[i] = rsqrtf((float)max(deg_out[i], 1));
}

// ---------------- x * out_norm -> bf16 (pre-scaled features) ----------------

__global__ __launch_bounds__(256) void scale_to_bf16_kernel(const float* __restrict__ x,
                                                            const float* __restrict__ out_norm,
                                                            uint2* __restrict__ hs) {
    int tid = blockIdx.x * 256 + threadIdx.x;   // one thread = 4 feats
    if (tid >= NNODES * 32) return;
    int row = tid >> 5, q = tid & 31;
    float nrm = out_norm[row];
    float4 v = *(const float4*)(x + (size_t)row * F + q * 4);
    uint2 o;
    o.x = (unsigned)f2bf(v.x * nrm) | ((unsigned)f2bf(v.y * nrm) << 16);
    o.y = (unsigned)f2bf(v.z * nrm) | ((unsigned)f2bf(v.w * nrm) << 16);
    hs[(size_t)row * 32 + q] = o;
}

// ---------------- weight pack: f32 [K][ncol] -> per-lane bf16 fragments ----------------
// Bp[((c*4 + s)*64 + lane)] = 8 bf16: W[s*32 + (lane>>4)*8 + j][c*16 + (lane&15)]

__global__ void pack_w_kernel(const float* __restrict__ W, short8* __restrict__ Bp, int ncol) {
    int idx = blockIdx.x * 256 + threadIdx.x;
    int total = (ncol / 16) * 4 * 64;
    if (idx >= total) return;
    int lane = idx & 63, s = (idx >> 6) & 3, c = idx >> 8;
    int n = c * 16 + (lane & 15);
    int k0 = s * 32 + (lane >> 4) * 8;
    short8 v;
#pragma unroll
    for (int j = 0; j < 8; j++) v[j] = (short)f2bf(W[(size_t)(k0 + j) * ncol + n]);
    Bp[idx] = v;
}

// ---------------- bucket offsets ----------------

__global__ void bucket_scan_kernel(const int* __restrict__ bucket_count,
                                   int* __restrict__ bucket_base,
                                   int* __restrict__ bucket_cursor) {
    __shared__ int s[256];
    int t = threadIdx.x;
    int v = (t < NB) ? bucket_count[t] : 0;
    s[t] = v;
    __syncthreads();
    for (int d = 1; d < 256; d <<= 1) {
        int u = (t >= d) ? s[t - d] : 0;
        __syncthreads();
        s[t] += u;
        __syncthreads();
    }
    if (t < NB) {
        int excl = s[t] - v;
        bucket_base[t] = excl;
        bucket_cursor[t] = excl;
        if (t == NB - 1) bucket_base[NB] = s[t];
    }
}

// ---------------- coarse scatter ----------------

__global__ __launch_bounds__(256) void bin_scatter_kernel(const int* __restrict__ src,
                                                          const int* __restrict__ dst,
                                                          int* __restrict__ bucket_cursor,
                                                          unsigned int* __restrict__ edges_binned) {
    __shared__ unsigned int pk[T2];
    __shared__ unsigned char bb[T2];
    __shared__ int hist[NB], base[NB], lcur[NB];
    int t = threadIdx.x;
    for (int i = t; i < NB; i += 256) { hist[i] = 0; lcur[i] = 0; }
    __syncthreads();
    int e0 = blockIdx.x * T2;
    int n = min(T2, NEDGES - e0);
    for (int i = t; i < n; i += 256) {
        int s = src[e0 + i], d = dst[e0 + i];
        int b = d >> 9;
        pk[i] = (unsigned)s | ((unsigned)(d & (NPB - 1)) << 17);
        bb[i] = (unsigned char)b;
        atomicAdd(&hist[b], 1);
    }
    __syncthreads();
    for (int b = t; b < NB; b += 256)
        if (hist[b] > 0) base[b] = atomicAdd(&bucket_cursor[b], hist[b]);
    __syncthreads();
    for (int i = t; i < n; i += 256) {
        int b = bb[i];
        int pos = base[b] + atomicAdd(&lcur[b], 1);
        edges_binned[pos] = pk[i];
    }
}

// ---------------- per-bucket fine CSR + in_norm ----------------

__global__ __launch_bounds__(512) void bucket_csr_kernel(const unsigned int* __restrict__ edges_binned,
                                                         const int* __restrict__ bucket_base,
                                                         int* __restrict__ row_ptr,
                                                         float* __restrict__ in_norm,
                                                         int* __restrict__ csr_src) {
    __shared__ int hist[NPB], off[NPB], lcur[NPB];
    int t = threadIdx.x;
    int b = blockIdx.x;
    hist[t] = 0; lcur[t] = 0;
    __syncthreads();
    int e0 = bucket_base[b], e1 = bucket_base[b + 1];
    for (int i = e0 + t; i < e1; i += 512)
        atomicAdd(&hist[edges_binned[i] >> 17], 1);
    __syncthreads();
    int h = hist[t];
    off[t] = h;
    __syncthreads();
    for (int d = 1; d < NPB; d <<= 1) {
        int u = (t >= d) ? off[t - d] : 0;
        __syncthreads();
        off[t] += u;
        __syncthreads();
    }
    int excl = off[t] - h;
    int node = b * NPB + t;
    if (node <= NNODES) row_ptr[node] = e0 + excl;
    if (node < NNODES) in_norm[node] = rsqrtf((float)max(h, 1));
    __syncthreads();
    off[t] = excl;
    __syncthreads();
    for (int i = e0 + t; i < e1; i += 512) {
        unsigned int p = edges_binned[i];
        int dl = p >> 17;
        int pos = e0 + off[dl] + atomicAdd(&lcur[dl], 1);
        csr_src[pos] = (int)(p & 0x1FFFF);
    }
}

// ---------------- aggregation (bf16 rows, fp32 accum) ----------------
// out[node] = bf16( in_norm[node] * sum_e hs[src_e] ), hs pre-scaled by out_norm

__global__ void aggregate_bf16_kernel(const unsigned* __restrict__ hs,
                                      const int* __restrict__ row_ptr,
                                      const int* __restrict__ csr_src,
                                      const float* __restrict__ in_norm,
                                      unsigned* __restrict__ out) {
    int wave = threadIdx.x >> 6;
    int lane = threadIdx.x & 63;
    int node = blockIdx.x * 4 + wave;
    if (node >= NNODES) return;
    int beg = row_ptr[node], end = row_ptr[node + 1];
    float ax = 0.f, ay = 0.f;
    int j = beg;
    for (; j + 4 <= end; j += 4) {
        int s0 = csr_src[j], s1 = csr_src[j + 1], s2 = csr_src[j + 2], s3 = csr_src[j + 3];
        unsigned u0 = hs[(size_t)s0 * 64 + lane];
        unsigned u1 = hs[(size_t)s1 * 64 + lane];
        unsigned u2 = hs[(size_t)s2 * 64 + lane];
        unsigned u3 = hs[(size_t)s3 * 64 + lane];
        ax += bflo(u0) + bflo(u1) + bflo(u2) + bflo(u3);
        ay += bfhi(u0) + bfhi(u1) + bfhi(u2) + bfhi(u3);
    }
    for (; j < end; j++) {
        unsigned u0 = hs[(size_t)csr_src[j] * 64 + lane];
        ax += bflo(u0);
        ay += bfhi(u0);
    }
    float inn = in_norm[node];
    out[(size_t)node * 64 + lane] =
        (unsigned)f2bf(ax * inn) | ((unsigned)f2bf(ay * inn) << 16);
}

// ---------------- MFMA GEMM: C[N x NCOL] = act(A[N x 128] @ W + b) ----------------
// A bf16 row-major, W pre-packed fragments. ACT: 1=relu->bf16, 2=sigmoid->f32.
// SCALE: multiply by out_norm[row] after act (feeds next aggregate).

template <int NCOL, int ACT, int SCALE>
__global__ __launch_bounds__(256) void gemm_mfma_kernel(const unsigned short* __restrict__ A,
                                                        const short8* __restrict__ Bp,
                                                        const float* __restrict__ bias,
                                                        const float* __restrict__ out_norm,
                                                        void* __restrict__ Cout, int nrows) {
    int w = threadIdx.x >> 6, lane = threadIdx.x & 63;
    int m = lane & 15, quad = lane >> 4;
    int row0 = blockIdx.x * 64 + w * 16;

    int arow = row0 + m;
    if (arow >= nrows) arow = nrows - 1;       // clamp: junk rows never stored
    short8 afrag[4];
#pragma unroll
    for (int s = 0; s < 4; s++)
        afrag[s] = *(const short8*)(A + (size_t)arow * F + s * 32 + quad * 8);

    int baseRow = row0 + quad * 4;
    float nrm[4];
    if (SCALE) {
#pragma unroll
        for (int r = 0; r < 4; r++) nrm[r] = out_norm[min(baseRow + r, nrows - 1)];
    }

#pragma unroll
    for (int c = 0; c < NCOL / 16; c++) {
        f32x4 acc = {0.f, 0.f, 0.f, 0.f};
#pragma unroll
        for (int s = 0; s < 4; s++) {
            short8 b = Bp[(c * 4 + s) * 64 + lane];
            acc = __builtin_amdgcn_mfma_f32_16x16x32_bf16(afrag[s], b, acc, 0, 0, 0);
        }
        float bc = bias[c * 16 + m];
#pragma unroll
        for (int r = 0; r < 4; r++) {
            int row = baseRow + r;
            if (row < nrows) {
                float v = acc[r] + bc;
                if (ACT == 1) {
                    v = fmaxf(v, 0.f);
                    if (SCALE) v *= nrm[r];
                    ((unsigned short*)Cout)[(size_t)row * NCOL + c * 16 + m] = f2bf(v);
                } else {
                    v = 1.f / (1.f + __expf(-v));
                    ((float*)Cout)[(size_t)row * NCOL + c * 16 + m] = v;
                }
            }
        }
    }
}

// ---------------- launch ----------------

extern "C" void kernel_launch(void* const* d_in, const int* in_sizes, int n_in,
                              void* d_out, int out_size, void* d_ws, size_t ws_size,
                              hipStream_t stream) {
    const float* x   = (const float*)d_in[0];
    const int* src   = (const int*)d_in[1];
    const int* dst   = (const int*)d_in[2];
    const float* W1  = (const float*)d_in[3];
    const float* b1  = (const float*)d_in[4];
    const float* W2  = (const float*)d_in[5];
    const float* b2  = (const float*)d_in[6];
    const float* Wm1 = (const float*)d_in[7];
    const float* bm1 = (const float*)d_in[8];
    const float* Wm2 = (const float*)d_in[9];
    const float* bm2 = (const float*)d_in[10];
    float* out = (float*)d_out;

    char* w = (char*)d_ws;
    int* deg_out      = (int*)w;   w += (size_t)NNODES * 4;
    int* bucket_count = (int*)w;   w += (size_t)(NB + 4) * 4;   // memset with deg_out
    float* out_norm   = (float*)w; w += (size_t)NNODES * 4;
    float* in_norm    = (float*)w; w += (size_t)NNODES * 4;
    int* row_ptr      = (int*)w;   w += (size_t)(NNODES + 4) * 4;
    int* bucket_base  = (int*)w;   w += (size_t)(NB + 4) * 4;
    int* bucket_cursor= (int*)w;   w += (size_t)(NB + 4) * 4;
    int* csr_src      = (int*)w;   w += (size_t)NEDGES * 4;
    short8* Wp1       = (short8*)w; w += 2048 * 16;
    short8* Wp2       = (short8*)w; w += 2048 * 16;
    short8* Wpm1      = (short8*)w; w += 2048 * 16;
    short8* Wpm2      = (short8*)w; w += 1024 * 16;
    unsigned* bufX    = (unsigned*)w; w += (size_t)NNODES * 64 * 4;  // bf16 N x 128
    unsigned* bufY    = (unsigned*)w; w += (size_t)NNODES * 64 * 4;  // bf16 N x 128
    // edges_binned (12.8 MB) aliases bufY: dead before first aggregate writes bufY
    unsigned int* edges_binned = (unsigned int*)bufY;

    const int nbN = (NNODES + 255) / 256;

    hipMemsetAsync(deg_out, 0, (size_t)(NNODES + NB + 4) * 4, stream);

    bin_count_kernel<<<1024, 256, 0, stream>>>(src, dst, deg_out, bucket_count);
    outnorm_kernel<<<nbN, 256, 0, stream>>>(deg_out, out_norm);
    scale_to_bf16_kernel<<<(NNODES * 32 + 255) / 256, 256, 0, stream>>>(x, out_norm, (uint2*)bufX);
    pack_w_kernel<<<8, 256, 0, stream>>>(W1, Wp1, 128);
    pack_w_kernel<<<8, 256, 0, stream>>>(W2, Wp2, 128);
    pack_w_kernel<<<8, 256, 0, stream>>>(Wm1, Wpm1, 128);
    pack_w_kernel<<<4, 256, 0, stream>>>(Wm2, Wpm2, 64);
    bucket_scan_kernel<<<1, 256, 0, stream>>>(bucket_count, bucket_base, bucket_cursor);
    bin_scatter_kernel<<<(NEDGES + T2 - 1) / T2, 256, 0, stream>>>(src, dst, bucket_cursor, edges_binned);
    bucket_csr_kernel<<<NB, 512, 0, stream>>>(edges_binned, bucket_base, row_ptr, in_norm, csr_src);

    const int aggGrid = NNODES / 4;
    const int gemmGrid = (NNODES + 63) / 64;

    // conv1
    aggregate_bf16_kernel<<<aggGrid, 256, 0, stream>>>(bufX, row_ptr, csr_src, in_norm, bufY);
    gemm_mfma_kernel<128, 1, 1><<<gemmGrid, 256, 0, stream>>>((const unsigned short*)bufY, Wp1, b1, out_norm, bufX, NNODES);
    // conv2
    aggregate_bf16_kernel<<<aggGrid, 256, 0, stream>>>(bufX, row_ptr, csr_src, in_norm, bufY);
    gemm_mfma_kernel<128, 1, 0><<<gemmGrid, 256, 0, stream>>>((const unsigned short*)bufY, Wp2, b2, out_norm, bufX, NNODES);
    // MLP head
    gemm_mfma_kernel<128, 1, 0><<<gemmGrid, 256, 0, stream>>>((const unsigned short*)bufX, Wpm1, bm1, out_norm, bufY, NNODES);
    gemm_mfma_kernel<64, 2, 0><<<gemmGrid, 256, 0, stream>>>((const unsigned short*)bufY, Wpm2, bm2, out_norm, out, NNODES);
}

// Round 4
// 587.723 us; speedup vs baseline: 2.3346x; 1.2193x over previous
//
#include <hip/hip_runtime.h>
#include <math.h>

#define NNODES 100000
#define NEDGES 3200000
#define F 128
#define NPB 512
#define NB ((NNODES + NPB - 1) / NPB)   // 196 buckets
#define CAP 20480                        // slots per bucket (mean 16326, 32 sigma margin)
#define T2 8192

typedef __attribute__((ext_vector_type(8))) short short8;
typedef __attribute__((ext_vector_type(4))) float f32x4;

__device__ __forceinline__ unsigned short f2bf(float f) {
    unsigned u = __float_as_uint(f);
    unsigned r = u + 0x7fff + ((u >> 16) & 1);
    return (unsigned short)(r >> 16);
}
__device__ __forceinline__ float bflo(unsigned u) { return __uint_as_float(u << 16); }
__device__ __forceinline__ float bfhi(unsigned u) { return __uint_as_float(u & 0xffff0000u); }

// ---------------- cursor init (CAP-strided bucket bases) ----------------

__global__ void init_cursors_kernel(int* __restrict__ dcur, int* __restrict__ scur) {
    int b = blockIdx.x * 256 + threadIdx.x;
    if (b < NB) { dcur[b] = b * CAP; scur[b] = b * CAP; }
}

// ---------------- dual binning: one edge read -> dst-keyed + src-keyed bins ----------------

__global__ __launch_bounds__(256) void dual_bin_kernel(const int* __restrict__ src,
                                                       const int* __restrict__ dst,
                                                       int* __restrict__ dcur,
                                                       int* __restrict__ scur,
                                                       unsigned* __restrict__ epk,
                                                       unsigned short* __restrict__ esl) {
    __shared__ unsigned pk[T2];
    __shared__ unsigned short sl[T2];
    __shared__ unsigned char db[T2], sb[T2];
    __shared__ int dh[NB], dbase[NB], dlc[NB];
    __shared__ int sh[NB], sbase[NB], slc[NB];
    int t = threadIdx.x;
    for (int i = t; i < NB; i += 256) { dh[i] = 0; dlc[i] = 0; sh[i] = 0; slc[i] = 0; }
    __syncthreads();
    int e0 = blockIdx.x * T2;
    int n = min(T2, NEDGES - e0);
    for (int i = t; i < n; i += 256) {
        int s = src[e0 + i], d = dst[e0 + i];
        int bd = d >> 9, bs = s >> 9;
        pk[i] = (unsigned)s | ((unsigned)(d & 511) << 17);
        sl[i] = (unsigned short)(s & 511);
        db[i] = (unsigned char)bd;
        sb[i] = (unsigned char)bs;
        atomicAdd(&dh[bd], 1);
        atomicAdd(&sh[bs], 1);
    }
    __syncthreads();
    for (int b = t; b < NB; b += 256) {
        if (dh[b]) dbase[b] = atomicAdd(&dcur[b], dh[b]);
        if (sh[b]) sbase[b] = atomicAdd(&scur[b], sh[b]);
    }
    __syncthreads();
    for (int i = t; i < n; i += 256) {
        int b = db[i];
        epk[dbase[b] + atomicAdd(&dlc[b], 1)] = pk[i];
    }
    for (int i = t; i < n; i += 256) {
        int b = sb[i];
        esl[sbase[b] + atomicAdd(&slc[b], 1)] = sl[i];
    }
}

// ---------------- out-degree -> out_norm (per-bucket LDS histogram) ----------------

__global__ __launch_bounds__(512) void src_hist_kernel(const unsigned short* __restrict__ esl,
                                                       const int* __restrict__ scur,
                                                       float* __restrict__ out_norm) {
    __shared__ int cnt[NPB];
    int t = threadIdx.x, b = blockIdx.x;
    cnt[t] = 0;
    __syncthreads();
    int e0 = b * CAP, e1 = scur[b];
    for (int i = e0 + t; i < e1; i += 512) atomicAdd(&cnt[esl[i]], 1);
    __syncthreads();
    int node = b * NPB + t;
    if (node < NNODES) out_norm[node] = rsqrtf((float)max(cnt[t], 1));
}

// ---------------- per-bucket fine CSR + in_norm (all-LDS cursors) ----------------

__global__ __launch_bounds__(512) void bucket_csr_kernel(const unsigned* __restrict__ epk,
                                                         const int* __restrict__ dcur,
                                                         int2* __restrict__ row_span,
                                                         float* __restrict__ in_norm,
                                                         int* __restrict__ csr_src) {
    __shared__ int hist[NPB], off[NPB], lcur[NPB];
    int t = threadIdx.x, b = blockIdx.x;
    hist[t] = 0; lcur[t] = 0;
    __syncthreads();
    int e0 = b * CAP, e1 = dcur[b];
    for (int i = e0 + t; i < e1; i += 512)
        atomicAdd(&hist[epk[i] >> 17], 1);
    __syncthreads();
    int h = hist[t];
    off[t] = h;
    __syncthreads();
    for (int d = 1; d < NPB; d <<= 1) {
        int u = (t >= d) ? off[t - d] : 0;
        __syncthreads();
        off[t] += u;
        __syncthreads();
    }
    int excl = off[t] - h;
    int node = b * NPB + t;
    if (node < NNODES) {
        row_span[node] = make_int2(e0 + excl, e0 + excl + h);
        in_norm[node] = rsqrtf((float)max(h, 1));
    }
    __syncthreads();
    off[t] = excl;
    __syncthreads();
    for (int i = e0 + t; i < e1; i += 512) {
        unsigned p = epk[i];
        int dl = p >> 17;
        csr_src[e0 + off[dl] + atomicAdd(&lcur[dl], 1)] = (int)(p & 0x1FFFF);
    }
}

// ---------------- x * out_norm -> bf16 ----------------

__global__ __launch_bounds__(256) void scale_to_bf16_kernel(const float* __restrict__ x,
                                                            const float* __restrict__ out_norm,
                                                            uint2* __restrict__ hs) {
    int tid = blockIdx.x * 256 + threadIdx.x;
    if (tid >= NNODES * 32) return;
    int row = tid >> 5, q = tid & 31;
    float nrm = out_norm[row];
    float4 v = *(const float4*)(x + (size_t)row * F + q * 4);
    uint2 o;
    o.x = (unsigned)f2bf(v.x * nrm) | ((unsigned)f2bf(v.y * nrm) << 16);
    o.y = (unsigned)f2bf(v.z * nrm) | ((unsigned)f2bf(v.w * nrm) << 16);
    hs[(size_t)row * 32 + q] = o;
}

// ---------------- pack all 4 weight matrices into MFMA B-fragments ----------------
// layout per matrix: Bp[(c*4+s)*64 + lane] = W[s*32+(lane>>4)*8+j][c*16+(lane&15)]

__global__ void pack_all_kernel(const float* __restrict__ W1, const float* __restrict__ W2,
                                const float* __restrict__ Wm1, const float* __restrict__ Wm2,
                                short8* __restrict__ Wp) {
    int idx = blockIdx.x * 256 + threadIdx.x;
    if (idx >= 7168) return;
    const float* W; int ncol, base;
    if (idx < 2048)      { W = W1;  ncol = 128; base = 0; }
    else if (idx < 4096) { W = W2;  ncol = 128; base = 2048; }
    else if (idx < 6144) { W = Wm1; ncol = 128; base = 4096; }
    else                 { W = Wm2; ncol = 64;  base = 6144; }
    int li = idx - base;
    int lane = li & 63, s = (li >> 6) & 3, c = li >> 8;
    int nn = c * 16 + (lane & 15);
    int k0 = s * 32 + (lane >> 4) * 8;
    short8 v;
#pragma unroll
    for (int j = 0; j < 8; j++) v[j] = (short)f2bf(W[(size_t)(k0 + j) * ncol + nn]);
    Wp[idx] = v;
}

// ---------------- aggregation: wave per node, 2 edges/gather-instr ----------------

__global__ void aggregate_kernel(const uint2* __restrict__ hs2,
                                 const int2* __restrict__ row_span,
                                 const int* __restrict__ csr_src,
                                 const float* __restrict__ in_norm,
                                 uint2* __restrict__ out2) {
    int wave = threadIdx.x >> 6;
    int lane = threadIdx.x & 63;
    int node = blockIdx.x * 4 + wave;
    if (node >= NNODES) return;
    int2 sp = row_span[node];
    int beg = sp.x, end = sp.y;
    int r = lane >> 5, c = lane & 31;
    float a0 = 0.f, a1 = 0.f, a2 = 0.f, a3 = 0.f;
    int j = beg;
    for (; j + 4 <= end; j += 4) {
        int sA = csr_src[j + r];
        int sB = csr_src[j + 2 + r];
        uint2 vA = hs2[(size_t)sA * 32 + c];
        uint2 vB = hs2[(size_t)sB * 32 + c];
        a0 += bflo(vA.x) + bflo(vB.x);
        a1 += bfhi(vA.x) + bfhi(vB.x);
        a2 += bflo(vA.y) + bflo(vB.y);
        a3 += bfhi(vA.y) + bfhi(vB.y);
    }
    for (; j < end; j += 2) {
        if (j + r < end) {
            int s = csr_src[j + r];
            uint2 v = hs2[(size_t)s * 32 + c];
            a0 += bflo(v.x); a1 += bfhi(v.x);
            a2 += bflo(v.y); a3 += bfhi(v.y);
        }
    }
    a0 += __shfl_xor(a0, 32);
    a1 += __shfl_xor(a1, 32);
    a2 += __shfl_xor(a2, 32);
    a3 += __shfl_xor(a3, 32);
    if (r == 0) {
        float inn = in_norm[node];
        uint2 o;
        o.x = (unsigned)f2bf(a0 * inn) | ((unsigned)f2bf(a1 * inn) << 16);
        o.y = (unsigned)f2bf(a2 * inn) | ((unsigned)f2bf(a3 * inn) << 16);
        out2[(size_t)node * 32 + c] = o;
    }
}

// ---------------- MFMA GEMM (conv layers): relu(A@W+b), optional *out_norm ----------------

template <int SCALE>
__global__ __launch_bounds__(256) void gemm_mfma_kernel(const unsigned short* __restrict__ A,
                                                        const short8* __restrict__ Bp,
                                                        const float* __restrict__ bias,
                                                        const float* __restrict__ out_norm,
                                                        unsigned short* __restrict__ Cout, int nrows) {
    int w = threadIdx.x >> 6, lane = threadIdx.x & 63;
    int m = lane & 15, quad = lane >> 4;
    int row0 = blockIdx.x * 64 + w * 16;

    int arow = min(row0 + m, nrows - 1);
    short8 afrag[4];
#pragma unroll
    for (int s = 0; s < 4; s++)
        afrag[s] = *(const short8*)(A + (size_t)arow * F + s * 32 + quad * 8);

    int baseRow = row0 + quad * 4;
    float nrm[4];
    if (SCALE) {
#pragma unroll
        for (int r = 0; r < 4; r++) nrm[r] = out_norm[min(baseRow + r, nrows - 1)];
    }

#pragma unroll
    for (int c = 0; c < 8; c++) {
        f32x4 acc = {0.f, 0.f, 0.f, 0.f};
#pragma unroll
        for (int s = 0; s < 4; s++) {
            short8 b = Bp[(c * 4 + s) * 64 + lane];
            acc = __builtin_amdgcn_mfma_f32_16x16x32_bf16(afrag[s], b, acc, 0, 0, 0);
        }
        float bc = bias[c * 16 + m];
#pragma unroll
        for (int r = 0; r < 4; r++) {
            int row = baseRow + r;
            if (row < nrows) {
                float v = fmaxf(acc[r] + bc, 0.f);
                if (SCALE) v *= nrm[r];
                Cout[(size_t)row * F + c * 16 + m] = f2bf(v);
            }
        }
    }
}

// ---------------- fused MLP head: sigmoid(relu(A@Wm1+bm1)@Wm2+bm2) ----------------

__global__ __launch_bounds__(256) void mlp_fused_kernel(const unsigned short* __restrict__ A,
                                                        const short8* __restrict__ Bp1,
                                                        const float* __restrict__ bm1,
                                                        const short8* __restrict__ Bp2,
                                                        const float* __restrict__ bm2,
                                                        float* __restrict__ out, int nrows) {
    __shared__ unsigned short h3[4][16][136];   // +8 pad: break bank conflicts
    int w = threadIdx.x >> 6, lane = threadIdx.x & 63;
    int m = lane & 15, quad = lane >> 4;
    int row0 = blockIdx.x * 64 + w * 16;

    int arow = min(row0 + m, nrows - 1);
    short8 afrag[4];
#pragma unroll
    for (int s = 0; s < 4; s++)
        afrag[s] = *(const short8*)(A + (size_t)arow * F + s * 32 + quad * 8);

#pragma unroll
    for (int c = 0; c < 8; c++) {
        f32x4 acc = {0.f, 0.f, 0.f, 0.f};
#pragma unroll
        for (int s = 0; s < 4; s++) {
            short8 b = Bp1[(c * 4 + s) * 64 + lane];
            acc = __builtin_amdgcn_mfma_f32_16x16x32_bf16(afrag[s], b, acc, 0, 0, 0);
        }
        float bc = bm1[c * 16 + m];
#pragma unroll
        for (int r = 0; r < 4; r++)
            h3[w][quad * 4 + r][c * 16 + m] = f2bf(fmaxf(acc[r] + bc, 0.f));
    }
    __syncthreads();

    short8 a2[4];
#pragma unroll
    for (int s = 0; s < 4; s++)
        a2[s] = *(const short8*)(&h3[w][m][s * 32 + quad * 8]);

    int baseRow = row0 + quad * 4;
#pragma unroll
    for (int c2 = 0; c2 < 4; c2++) {
        f32x4 acc = {0.f, 0.f, 0.f, 0.f};
#pragma unroll
        for (int s = 0; s < 4; s++) {
            short8 b = Bp2[(c2 * 4 + s) * 64 + lane];
            acc = __builtin_amdgcn_mfma_f32_16x16x32_bf16(a2[s], b, acc, 0, 0, 0);
        }
        float bc = bm2[c2 * 16 + m];
#pragma unroll
        for (int r = 0; r < 4; r++) {
            int row = baseRow + r;
            if (row < nrows)
                out[(size_t)row * 64 + c2 * 16 + m] = 1.f / (1.f + __expf(-(acc[r] + bc)));
        }
    }
}

// ---------------- launch ----------------

extern "C" void kernel_launch(void* const* d_in, const int* in_sizes, int n_in,
                              void* d_out, int out_size, void* d_ws, size_t ws_size,
                              hipStream_t stream) {
    const float* x   = (const float*)d_in[0];
    const int* src   = (const int*)d_in[1];
    const int* dst   = (const int*)d_in[2];
    const float* W1  = (const float*)d_in[3];
    const float* b1  = (const float*)d_in[4];
    const float* W2  = (const float*)d_in[5];
    const float* b2  = (const float*)d_in[6];
    const float* Wm1 = (const float*)d_in[7];
    const float* bm1 = (const float*)d_in[8];
    const float* Wm2 = (const float*)d_in[9];
    const float* bm2 = (const float*)d_in[10];
    float* out = (float*)d_out;

    char* w = (char*)d_ws;
    int* dcur          = (int*)w;   w += (size_t)(NB + 4) * 4;
    int* scur          = (int*)w;   w += (size_t)(NB + 4) * 4;
    float* out_norm    = (float*)w; w += (size_t)NNODES * 4;
    float* in_norm     = (float*)w; w += (size_t)NNODES * 4;
    int2* row_span     = (int2*)w;  w += (size_t)NNODES * 8;
    int* csr_src       = (int*)w;   w += (size_t)NB * CAP * 4;
    unsigned* epk      = (unsigned*)w; w += (size_t)NB * CAP * 4;
    unsigned short* esl= (unsigned short*)w; w += (size_t)NB * CAP * 2;
    short8* Wp         = (short8*)w; w += (size_t)7168 * 16;
    uint2* bufX        = (uint2*)w; w += (size_t)NNODES * 32 * 8;
    uint2* bufY        = (uint2*)w; w += (size_t)NNODES * 32 * 8;

    init_cursors_kernel<<<1, 256, 0, stream>>>(dcur, scur);
    dual_bin_kernel<<<(NEDGES + T2 - 1) / T2, 256, 0, stream>>>(src, dst, dcur, scur, epk, esl);
    src_hist_kernel<<<NB, 512, 0, stream>>>(esl, scur, out_norm);
    bucket_csr_kernel<<<NB, 512, 0, stream>>>(epk, dcur, row_span, in_norm, csr_src);
    scale_to_bf16_kernel<<<(NNODES * 32 + 255) / 256, 256, 0, stream>>>(x, out_norm, bufX);
    pack_all_kernel<<<28, 256, 0, stream>>>(W1, W2, Wm1, Wm2, Wp);

    const int aggGrid = NNODES / 4;
    const int gemmGrid = (NNODES + 63) / 64;

    aggregate_kernel<<<aggGrid, 256, 0, stream>>>(bufX, row_span, csr_src, in_norm, bufY);
    gemm_mfma_kernel<1><<<gemmGrid, 256, 0, stream>>>((const unsigned short*)bufY, Wp, b1, out_norm,
                                                      (unsigned short*)bufX, NNODES);
    aggregate_kernel<<<aggGrid, 256, 0, stream>>>(bufX, row_span, csr_src, in_norm, bufY);
    gemm_mfma_kernel<0><<<gemmGrid, 256, 0, stream>>>((const unsigned short*)bufY, Wp + 2048, b2, out_norm,
                                                      (unsigned short*)bufX, NNODES);
    mlp_fused_kernel<<<gemmGrid, 256, 0, stream>>>((const unsigned short*)bufX, Wp + 4096, bm1,
                                                   Wp + 6144, bm2, out, NNODES);
}